// Round 19
// baseline (49.434 us; speedup 1.0000x reference)
//
#include <hip/hip_runtime.h>

// DifferenceCost, two-pass, fragment-major workspace:
//  Pass A: fp32 [b][c][h][w] -> bf16 MFMA-fragment layout
//          frag[b][row][qtile(12)][kc(4)][lane(64)] (16B per lane), plus
//          per-pixel sum-of-squares planes R2/T2 (on bf16-rounded values).
//  Pass B (corrcost18): R18's grid (ig innermost -> L2-local ws reads), but
//          ALL 3 rows' center tiles staged up-front (12 GLL16/wave, max MLP)
//          with ONE barrier per block; compute then runs barrier-free.
//          LDS 51KB -> 3 blocks/CU. cost = sqrt(max(R2+T2-2X,0)).
// Falls back to round-3 single-kernel path if ws too small.

#define B_N 4
#define C_N 128
#define H_N 96
#define W_N 192
#define TPLANE (H_N * W_N)                 // 18432
#define CPLANE ((size_t)C_N * TPLANE)

#define FRAG_ROW_SZ ((size_t)12 * 4 * 1024)          // 49152 B per (b,row)
#define BF_SZ   ((size_t)B_N * H_N * FRAG_ROW_SZ)    // 18,874,368
#define REFF_OFF ((size_t)0)
#define TGTF_OFF BF_SZ
#define SQ_SZ   ((size_t)B_N * TPLANE * 4)
#define R2_OFF  (2 * BF_SZ)
#define T2_OFF  (R2_OFF + SQ_SZ)
#define WS_NEED (T2_OFF + SQ_SZ)                     // 38,338,560 B

using f32x4 = __attribute__((ext_vector_type(4))) float;
using s16x8 = __attribute__((ext_vector_type(8))) short;

typedef const __attribute__((address_space(1))) void* gas1_t;
typedef __attribute__((address_space(3))) void* las3_t;
#define GLL16(gp, lp) __builtin_amdgcn_global_load_lds((gas1_t)(gp), (las3_t)(lp), 16, 0, 0)

__device__ __forceinline__ short f2bf(float x) {
    unsigned u = __builtin_bit_cast(unsigned, x);
    u = (u + 0x7fffu + ((u >> 16) & 1u)) >> 16;   // RNE; inputs finite
    return (short)(unsigned short)u;
}
__device__ __forceinline__ float bf2f(short s) {
    return __builtin_bit_cast(float, ((unsigned)(unsigned short)s) << 16);
}

// ---------------- Pass A: convert + fragment-major store + squared sums ----
__global__ __launch_bounds__(256, 4)
void convert_frag(const float* __restrict__ ref, const float* __restrict__ tgt,
                  unsigned char* __restrict__ ws)
{
    __shared__ unsigned int l32[64][65];   // [w][c-pair], stride 65 -> no conflicts

    const int tid = threadIdx.x;
    // bijective XCD chunk swizzle, (b,h)-major order shared with pass B
    const int bid = blockIdx.x;
    const int u2  = (bid & 7) * 144 + (bid >> 3);   // 1152 = 8 x 144
    const int wc  = u2 % 3;               // which 64-w chunk
    const int h   = (u2 / 3) % H_N;
    const int b   = u2 / (3 * H_N);
    const int w0  = wc * 64;
    const int isT = blockIdx.y;

    const float* src = (isT ? tgt : ref) + (size_t)b * CPLANE + h * W_N + w0;
    unsigned char* dstF = ws + (isT ? TGTF_OFF : REFF_OFF);
    float* sq = (float*)(ws + (isT ? T2_OFF : R2_OFF));

    // phase 1: coalesced fp32 read, convert, pack pairs into LDS
    const int w  = tid & 63;
    const int cq = tid >> 6;
#pragma unroll
    for (int batch = 0; batch < 16; ++batch) {
        int cp = batch * 4 + cq;
        float v0 = src[(size_t)(2 * cp + 0) * TPLANE + w];
        float v1 = src[(size_t)(2 * cp + 1) * TPLANE + w];
        unsigned u = ((unsigned)(unsigned short)f2bf(v0))
                   | ((unsigned)(unsigned short)f2bf(v1) << 16);
        l32[w][cp] = u;
    }
    __syncthreads();

    // phase 2: fragment-major store; each wave-iter writes 1KB contiguous.
#pragma unroll
    for (int it = 0; it < 4; ++it) {
        int idx   = it * 256 + tid;        // 0..1023
        int lane2 = idx & 63;
        int kc    = (idx >> 6) & 3;
        int qt_l  = idx >> 8;              // 0..3
        int w_l   = qt_l * 16 + (lane2 & 15);
        int cp0   = kc * 16 + (lane2 >> 4) * 4;
        uint4 d = make_uint4(l32[w_l][cp0], l32[w_l][cp0 + 1],
                             l32[w_l][cp0 + 2], l32[w_l][cp0 + 3]);
        int qt = wc * 4 + qt_l;
        size_t off = (((size_t)(b * H_N + h) * 12 + qt) * 4 + kc) * 1024
                   + (size_t)lane2 * 16;
        *(uint4*)(dstF + off) = d;
    }

    // phase 3: per-pixel sum of squares (bf16-rounded)
    const int cs = tid & 15;
#pragma unroll
    for (int pass = 0; pass < 4; ++pass) {
        int wr = pass * 16 + (tid >> 4);
        float s = 0.f;
#pragma unroll
        for (int k2 = 0; k2 < 4; ++k2) {
            unsigned u = l32[wr][cs * 4 + k2];
            float lo = __builtin_bit_cast(float, u << 16);
            float hi = __builtin_bit_cast(float, u & 0xffff0000u);
            s = fmaf(lo, lo, fmaf(hi, hi, s));
        }
        s += __shfl_xor(s, 1); s += __shfl_xor(s, 2);
        s += __shfl_xor(s, 4); s += __shfl_xor(s, 8);
        if (cs == 0) sq[(size_t)(b * TPLANE + h * W_N + w0 + wr)] = s;
    }
}

// ---------------- Pass B: all-rows staged, ONE barrier, ig innermost -------
#define MFMA_B16 __builtin_amdgcn_mfma_f32_16x16x32_bf16

__global__ __launch_bounds__(256)
void corrcost18(const unsigned char* __restrict__ ws, float* __restrict__ out)
{
    __shared__ unsigned char stageB[3][4 * 4096];   // 3 rows x 4 center qtiles
    __shared__ float ldsx[4][16][12];               // extract transpose, 3 KiB

    const int tid  = threadIdx.x;
    const int lane = tid & 63;
    const int wv   = tid >> 6;
    const int col  = lane & 15;
    const int grp  = lane >> 4;

    // 3456 blocks = 8 XCDs x 432 (bijective). u = ((b*96+h)*3+wtg)*3+ig:
    // ig innermost -> all readers of a tgt row temporally adjacent (L2-hot).
    const int blk = blockIdx.x;
    const int u   = (blk & 7) * 432 + (blk >> 3);
    const int ig  = u % 3;
    const int r3  = u / 3;
    const int wtg = r3 % 3;
    const int v3  = r3 / 3;
    const int h   = v3 % 96;
    const int b   = v3 / 96;
    const int bT  = b * TPLANE;

    const int wt0 = wtg * 4;
    const int wt  = wt0 + wv;
    const int w0  = wt * 16;

    const bool dok0 = (wt >= 1);
    const bool dok2 = (wt <= 10);
    // this wave's edge qtile (outside the staged 4 center tiles), if any
    const int eq = (wv == 0) ? (wt0 - 1) : ((wv == 3) ? (wt0 + 4) : -1);
    const bool eok = (unsigned)eq < 12u;

    const unsigned char* tgtF = ws + TGTF_OFF;
    const int rowbase = h + ig * 3 - 4;

    // ---- stage ALL 3 rows' center tiles (up to 12 GLL16/wave, back-to-back)
#pragma unroll
    for (int tt = 0; tt < 3; ++tt) {
        const int row = rowbase + tt;
        if ((unsigned)row < (unsigned)H_N) {
            const unsigned char* fB = tgtF + (size_t)(b * H_N + row) * FRAG_ROW_SZ
                                    + (size_t)(wt0 + wv) * 4096 + (size_t)lane * 16;
            unsigned char* lp = &stageB[tt][0] + wv * 4096;
            GLL16(fB,        lp);
            GLL16(fB + 1024, lp + 1024);
            GLL16(fB + 2048, lp + 2048);
            GLL16(fB + 3072, lp + 3072);
        }
    }

    // A fragments + R2 (vector loads overlap the DMA flight)
    const unsigned char* fA = ws + REFF_OFF
        + ((size_t)(b * H_N + h) * 12 + wt) * 4096 + (size_t)lane * 16;
    const s16x8 A0 = *(const s16x8*)(fA);
    const s16x8 A1 = *(const s16x8*)(fA + 1024);
    const s16x8 A2 = *(const s16x8*)(fA + 2048);
    const s16x8 A3 = *(const s16x8*)(fA + 3072);

    const float* r2p = (const float*)(ws + R2_OFF) + bT + h * W_N + w0;
    const f32x4 r2v = *(const f32x4*)(r2p + grp * 4);

    const float* t2pl = (const float*)(ws + T2_OFF) + bT;

    float* outb = out + (size_t)b * 81 * TPLANE + (size_t)ig * 27 * TPLANE
                + h * W_N + w0;
    const size_t so0 = (size_t)grp * TPLANE + col;        // j=grp
    const size_t so1 = (size_t)(4 + grp) * TPLANE + col;  // j=4+grp
    const size_t so2 = (size_t)8 * TPLANE + col;          // j=8

    __syncthreads();       // ONE barrier: drains all DMA, staged data visible

    // ---- compute all 3 rows, barrier-free ----
#pragma unroll
    for (int tt = 0; tt < 3; ++tt) {
        const int row = rowbase + tt;
        const bool rok = (unsigned)row < (unsigned)H_N;   // block-uniform

        f32x4 acc0 = {0.f, 0.f, 0.f, 0.f}, acc1 = acc0, acc2 = acc0;
        float t20 = 0.f, t21 = 0.f, t22 = 0.f;

        if (rok) {
            const float* t2r = t2pl + row * W_N;
            // edge tile regs (wv0 left / wv3 right only), issued early (L2-hot)
            s16x8 E0, E1, E2, E3;
            if (eok) {
                const unsigned char* ep = tgtF
                    + (size_t)(b * H_N + row) * FRAG_ROW_SZ
                    + (size_t)eq * 4096 + (size_t)lane * 16;
                E0 = *(const s16x8*)(ep);
                E1 = *(const s16x8*)(ep + 1024);
                E2 = *(const s16x8*)(ep + 2048);
                E3 = *(const s16x8*)(ep + 3072);
            }
            if (dok0) t20 = t2r[(wt - 1) * 16 + col];
            t21 = t2r[wt * 16 + col];
            if (dok2) t22 = t2r[(wt + 1) * 16 + col];

            const unsigned char* sb = &stageB[tt][0] + (size_t)lane * 16;
            // d=1 (center, staged index wv) — always staged, do first
            {
                const unsigned char* p = sb + (size_t)wv * 4096;
                const s16x8 B0 = *(const s16x8*)(p);
                const s16x8 B1 = *(const s16x8*)(p + 1024);
                const s16x8 B2 = *(const s16x8*)(p + 2048);
                const s16x8 B3 = *(const s16x8*)(p + 3072);
                acc1 = MFMA_B16(A0, B0, acc1, 0, 0, 0);
                acc1 = MFMA_B16(A1, B1, acc1, 0, 0, 0);
                acc1 = MFMA_B16(A2, B2, acc1, 0, 0, 0);
                acc1 = MFMA_B16(A3, B3, acc1, 0, 0, 0);
            }
            // d=2 (staged for wv<3; edge regs for wv==3)
            if (dok2) {
                if (wv < 3) {
                    const unsigned char* p = sb + (size_t)(wv + 1) * 4096;
                    const s16x8 B0 = *(const s16x8*)(p);
                    const s16x8 B1 = *(const s16x8*)(p + 1024);
                    const s16x8 B2 = *(const s16x8*)(p + 2048);
                    const s16x8 B3 = *(const s16x8*)(p + 3072);
                    acc2 = MFMA_B16(A0, B0, acc2, 0, 0, 0);
                    acc2 = MFMA_B16(A1, B1, acc2, 0, 0, 0);
                    acc2 = MFMA_B16(A2, B2, acc2, 0, 0, 0);
                    acc2 = MFMA_B16(A3, B3, acc2, 0, 0, 0);
                } else {
                    acc2 = MFMA_B16(A0, E0, acc2, 0, 0, 0);
                    acc2 = MFMA_B16(A1, E1, acc2, 0, 0, 0);
                    acc2 = MFMA_B16(A2, E2, acc2, 0, 0, 0);
                    acc2 = MFMA_B16(A3, E3, acc2, 0, 0, 0);
                }
            }
            // d=0 (staged for wv>0; edge regs for wv==0) — edge last
            if (dok0) {
                if (wv > 0) {
                    const unsigned char* p = sb + (size_t)(wv - 1) * 4096;
                    const s16x8 B0 = *(const s16x8*)(p);
                    const s16x8 B1 = *(const s16x8*)(p + 1024);
                    const s16x8 B2 = *(const s16x8*)(p + 2048);
                    const s16x8 B3 = *(const s16x8*)(p + 3072);
                    acc0 = MFMA_B16(A0, B0, acc0, 0, 0, 0);
                    acc0 = MFMA_B16(A1, B1, acc0, 0, 0, 0);
                    acc0 = MFMA_B16(A2, B2, acc0, 0, 0, 0);
                    acc0 = MFMA_B16(A3, B3, acc0, 0, 0, 0);
                } else {
                    acc0 = MFMA_B16(A0, E0, acc0, 0, 0, 0);
                    acc0 = MFMA_B16(A1, E1, acc0, 0, 0, 0);
                    acc0 = MFMA_B16(A2, E2, acc0, 0, 0, 0);
                    acc0 = MFMA_B16(A3, E3, acc0, 0, 0, 0);
                }
            }
        }

        // ---- extract: D col = lane&15 (q in tile), D row = grp*4+pp (w) ----
#pragma unroll
        for (int d = 0; d < 3; ++d) {
            const bool dok = (d == 0) ? dok0 : ((d == 1) ? true : dok2);
            const f32x4 ac = (d == 0) ? acc0 : ((d == 1) ? acc1 : acc2);
            const float t2 = (d == 0) ? t20 : ((d == 1) ? t21 : t22);
#pragma unroll
            for (int pp = 0; pp < 4; ++pp) {
                const int wl = grp * 4 + pp;
                const int j  = 16 * (d - 1) + col - wl + 4;
                if ((unsigned)j < 9u) {
                    float val = 0.f;
                    if (rok && dok) {
                        float cs_ = r2v[pp] + t2 - 2.f * ac[pp];
                        val = __builtin_amdgcn_sqrtf(fmaxf(cs_, 0.f));
                    }
                    ldsx[wv][wl][j] = val;   // within-wave use only
                }
            }
        }

        float* ob = outb + (size_t)tt * 9 * TPLANE;
        float v0 = ldsx[wv][col][grp];
        float v1 = ldsx[wv][col][4 + grp];
        ob[so0] = v0;
        ob[so1] = v1;
        if (lane < 16) ob[so2] = ldsx[wv][col][8];
    }
}

// ---------------- Fallback (round-3 kernel, used if ws too small) ----------
__global__ __launch_bounds__(256, 4)
void corrcost3(const float* __restrict__ ref,
               const float* __restrict__ tgt,
               float* __restrict__ out)
{
    const int tid  = threadIdx.x;
    const int lane = tid & 63;
    const int wv   = tid >> 6;
    const int bid = blockIdx.x;
    const int swz = (bid & 7) * 1296 + (bid >> 3);
    const int u   = swz * 4 + wv;
    const int i   = u % 9;
    const int v9  = u / 9;
    const int wt  = v9 % 12;
    const int v12 = v9 / 12;
    const int h   = v12 % 96;
    const int b   = v12 / 96;
    const int w0  = wt * 16;
    const int q0  = w0 - 8;
    const int row = h + i - 4;
    const bool rok = (unsigned)row < (unsigned)H_N;

    const float* ref_b = ref + (size_t)b * CPLANE;
    const float* tgt_b = tgt + (size_t)b * CPLANE;
    float* out_b = out + (size_t)b * 81 * TPLANE;
    const int col = lane & 15;
    const int ke  = (lane >> 4) * 8;

    s16x8 A[4];
    float r2p = 0.f;
    const float* aptr = ref_b + (size_t)ke * TPLANE + h * W_N + w0 + col;
#pragma unroll
    for (int kc = 0; kc < 4; ++kc) {
#pragma unroll
        for (int e = 0; e < 8; ++e) {
            float v = aptr[(size_t)(kc * 32 + e) * TPLANE];
            short s = f2bf(v);
            float vb = bf2f(s);
            r2p = fmaf(vb, vb, r2p);
            A[kc][e] = s;
        }
    }
    r2p += __shfl_xor(r2p, 16);
    r2p += __shfl_xor(r2p, 32);
    float r2r[4];
#pragma unroll
    for (int pp = 0; pp < 4; ++pp)
        r2r[pp] = __shfl(r2p, (lane >> 4) * 4 + pp);

    f32x4 acc0 = {0.f, 0.f, 0.f, 0.f}, acc1 = acc0;
    float t20 = 0.f, t21 = 0.f;
    if (rok) {
        const float* bbase = tgt_b + (size_t)ke * TPLANE + (size_t)row * W_N;
#pragma unroll
        for (int t = 0; t < 2; ++t) {
            const int q = q0 + t * 16 + col;
            const bool qok = (unsigned)q < (unsigned)W_N;
            const float* bptr = bbase + q;
            s16x8 Bf[4];
            float t2p = 0.f;
#pragma unroll
            for (int kc = 0; kc < 4; ++kc) {
#pragma unroll
                for (int e = 0; e < 8; ++e) {
                    float v = qok ? bptr[(size_t)(kc * 32 + e) * TPLANE] : 0.f;
                    short s = f2bf(v);
                    float vb = bf2f(s);
                    t2p = fmaf(vb, vb, t2p);
                    Bf[kc][e] = s;
                }
            }
            t2p += __shfl_xor(t2p, 16);
            t2p += __shfl_xor(t2p, 32);
            if (t == 0) {
                t20 = t2p;
#pragma unroll
                for (int kc = 0; kc < 4; ++kc)
                    acc0 = MFMA_B16(A[kc], Bf[kc], acc0, 0, 0, 0);
            } else {
                t21 = t2p;
#pragma unroll
                for (int kc = 0; kc < 4; ++kc)
                    acc1 = MFMA_B16(A[kc], Bf[kc], acc1, 0, 0, 0);
            }
        }
    }
#pragma unroll
    for (int t = 0; t < 2; ++t) {
        const int q = q0 + t * 16 + col;
        const bool qok = (unsigned)q < (unsigned)W_N;
        const f32x4 a = t ? acc1 : acc0;
        const float t2 = t ? t21 : t20;
#pragma unroll
        for (int pp = 0; pp < 4; ++pp) {
            const int wl = (lane >> 4) * 4 + pp;
            const int j  = q - (w0 + wl) + 4;
            if ((unsigned)j < 9u) {
                float val = 0.f;
                if (rok && qok) {
                    float cs = r2r[pp] + t2 - 2.f * a[pp];
                    val = cs > 0.f ? sqrtf(cs) : 0.f;
                }
                out_b[(size_t)(i * 9 + j) * TPLANE + h * W_N + w0 + wl] = val;
            }
        }
    }
}

extern "C" void kernel_launch(void* const* d_in, const int* in_sizes, int n_in,
                              void* d_out, int out_size, void* d_ws, size_t ws_size,
                              hipStream_t stream) {
    const float* ref = (const float*)d_in[0];
    const float* tgt = (const float*)d_in[1];
    float* out = (float*)d_out;

    if (ws_size >= WS_NEED && d_ws != nullptr) {
        unsigned char* ws = (unsigned char*)d_ws;
        convert_frag<<<dim3(3 * H_N * B_N, 2), dim3(256), 0, stream>>>(ref, tgt, ws);
        corrcost18<<<dim3(3456), dim3(256), 0, stream>>>(ws, out);
    } else {
        corrcost3<<<dim3(10368), dim3(256), 0, stream>>>(ref, tgt, out);
    }
}

// Round 20
// 47.766 us; speedup vs baseline: 1.0349x; 1.0349x over previous
//
#include <hip/hip_runtime.h>

// DifferenceCost, two-pass, fragment-major workspace:
//  Pass A: fp32 [b][c][h][w] -> bf16 MFMA-fragment layout
//          frag[b][row][qtile(12)][kc(4)][lane(64)] (16B per lane), plus
//          per-pixel sum-of-squares planes R2/T2 (on bf16-rounded values).
//  Pass B (corrcost19): ig-innermost L2-hot grid (R18's win) + R15's
//          double-buffered 4-center-tile staging: ONE barrier per row,
//          stage(t+1) issued before compute(t) -> DMA flies under MFMAs.
//          Edge qtiles (wv0/wv3) global->registers. LDS 35KB -> 4 blocks/CU.
// Falls back to round-3 single-kernel path if ws too small.

#define B_N 4
#define C_N 128
#define H_N 96
#define W_N 192
#define TPLANE (H_N * W_N)                 // 18432
#define CPLANE ((size_t)C_N * TPLANE)

#define FRAG_ROW_SZ ((size_t)12 * 4 * 1024)          // 49152 B per (b,row)
#define BF_SZ   ((size_t)B_N * H_N * FRAG_ROW_SZ)    // 18,874,368
#define REFF_OFF ((size_t)0)
#define TGTF_OFF BF_SZ
#define SQ_SZ   ((size_t)B_N * TPLANE * 4)
#define R2_OFF  (2 * BF_SZ)
#define T2_OFF  (R2_OFF + SQ_SZ)
#define WS_NEED (T2_OFF + SQ_SZ)                     // 38,338,560 B

using f32x4 = __attribute__((ext_vector_type(4))) float;
using s16x8 = __attribute__((ext_vector_type(8))) short;

typedef const __attribute__((address_space(1))) void* gas1_t;
typedef __attribute__((address_space(3))) void* las3_t;
#define GLL16(gp, lp) __builtin_amdgcn_global_load_lds((gas1_t)(gp), (las3_t)(lp), 16, 0, 0)

__device__ __forceinline__ short f2bf(float x) {
    unsigned u = __builtin_bit_cast(unsigned, x);
    u = (u + 0x7fffu + ((u >> 16) & 1u)) >> 16;   // RNE; inputs finite
    return (short)(unsigned short)u;
}
__device__ __forceinline__ float bf2f(short s) {
    return __builtin_bit_cast(float, ((unsigned)(unsigned short)s) << 16);
}

// ---------------- Pass A: convert + fragment-major store + squared sums ----
__global__ __launch_bounds__(256, 4)
void convert_frag(const float* __restrict__ ref, const float* __restrict__ tgt,
                  unsigned char* __restrict__ ws)
{
    __shared__ unsigned int l32[64][65];   // [w][c-pair], stride 65 -> no conflicts

    const int tid = threadIdx.x;
    // bijective XCD chunk swizzle, (b,h)-major order shared with pass B
    const int bid = blockIdx.x;
    const int u2  = (bid & 7) * 144 + (bid >> 3);   // 1152 = 8 x 144
    const int wc  = u2 % 3;               // which 64-w chunk
    const int h   = (u2 / 3) % H_N;
    const int b   = u2 / (3 * H_N);
    const int w0  = wc * 64;
    const int isT = blockIdx.y;

    const float* src = (isT ? tgt : ref) + (size_t)b * CPLANE + h * W_N + w0;
    unsigned char* dstF = ws + (isT ? TGTF_OFF : REFF_OFF);
    float* sq = (float*)(ws + (isT ? T2_OFF : R2_OFF));

    // phase 1: coalesced fp32 read, convert, pack pairs into LDS
    const int w  = tid & 63;
    const int cq = tid >> 6;
#pragma unroll
    for (int batch = 0; batch < 16; ++batch) {
        int cp = batch * 4 + cq;
        float v0 = src[(size_t)(2 * cp + 0) * TPLANE + w];
        float v1 = src[(size_t)(2 * cp + 1) * TPLANE + w];
        unsigned u = ((unsigned)(unsigned short)f2bf(v0))
                   | ((unsigned)(unsigned short)f2bf(v1) << 16);
        l32[w][cp] = u;
    }
    __syncthreads();

    // phase 2: fragment-major store; each wave-iter writes 1KB contiguous.
#pragma unroll
    for (int it = 0; it < 4; ++it) {
        int idx   = it * 256 + tid;        // 0..1023
        int lane2 = idx & 63;
        int kc    = (idx >> 6) & 3;
        int qt_l  = idx >> 8;              // 0..3
        int w_l   = qt_l * 16 + (lane2 & 15);
        int cp0   = kc * 16 + (lane2 >> 4) * 4;
        uint4 d = make_uint4(l32[w_l][cp0], l32[w_l][cp0 + 1],
                             l32[w_l][cp0 + 2], l32[w_l][cp0 + 3]);
        int qt = wc * 4 + qt_l;
        size_t off = (((size_t)(b * H_N + h) * 12 + qt) * 4 + kc) * 1024
                   + (size_t)lane2 * 16;
        *(uint4*)(dstF + off) = d;
    }

    // phase 3: per-pixel sum of squares (bf16-rounded)
    const int cs = tid & 15;
#pragma unroll
    for (int pass = 0; pass < 4; ++pass) {
        int wr = pass * 16 + (tid >> 4);
        float s = 0.f;
#pragma unroll
        for (int k2 = 0; k2 < 4; ++k2) {
            unsigned u = l32[wr][cs * 4 + k2];
            float lo = __builtin_bit_cast(float, u << 16);
            float hi = __builtin_bit_cast(float, u & 0xffff0000u);
            s = fmaf(lo, lo, fmaf(hi, hi, s));
        }
        s += __shfl_xor(s, 1); s += __shfl_xor(s, 2);
        s += __shfl_xor(s, 4); s += __shfl_xor(s, 8);
        if (cs == 0) sq[(size_t)(b * TPLANE + h * W_N + w0 + wr)] = s;
    }
}

// ---------------- Pass B: dbuf 1-barrier/row, ig-innermost grid ------------
#define MFMA_B16 __builtin_amdgcn_mfma_f32_16x16x32_bf16

__global__ __launch_bounds__(256)
void corrcost19(const unsigned char* __restrict__ ws, float* __restrict__ out)
{
    __shared__ unsigned char stageB[2][4 * 4096];   // 2 x 16 KiB center tiles
    __shared__ float ldsx[4][16][12];               // extract transpose, 3 KiB

    const int tid  = threadIdx.x;
    const int lane = tid & 63;
    const int wv   = tid >> 6;
    const int col  = lane & 15;
    const int grp  = lane >> 4;

    // 3456 blocks = 8 XCDs x 432 (bijective). u = ((b*96+h)*3+wtg)*3+ig:
    // ig innermost -> all readers of a tgt row temporally adjacent (L2-hot).
    const int blk = blockIdx.x;
    const int u   = (blk & 7) * 432 + (blk >> 3);
    const int ig  = u % 3;
    const int r3  = u / 3;
    const int wtg = r3 % 3;
    const int v3  = r3 / 3;
    const int h   = v3 % 96;
    const int b   = v3 / 96;
    const int bT  = b * TPLANE;

    const int wt0 = wtg * 4;
    const int wt  = wt0 + wv;
    const int w0  = wt * 16;

    const bool dok0 = (wt >= 1);
    const bool dok2 = (wt <= 10);
    // this wave's edge qtile (outside the staged 4 center tiles), if any
    const int eq = (wv == 0) ? (wt0 - 1) : ((wv == 3) ? (wt0 + 4) : -1);
    const bool eok = (unsigned)eq < 12u;

    const unsigned char* tgtF = ws + TGTF_OFF;
    const int rowbase = h + ig * 3 - 4;

    // prologue: stage center tiles of row 0 into buf 0 (4 GLL16 per wave)
    {
        const int row0 = rowbase;
        if ((unsigned)row0 < (unsigned)H_N) {
            const unsigned char* fB = tgtF + (size_t)(b * H_N + row0) * FRAG_ROW_SZ
                                    + (size_t)(wt0 + wv) * 4096 + (size_t)lane * 16;
            unsigned char* lp = &stageB[0][0] + wv * 4096;
            GLL16(fB,        lp);
            GLL16(fB + 1024, lp + 1024);
            GLL16(fB + 2048, lp + 2048);
            GLL16(fB + 3072, lp + 3072);
        }
    }

    // A fragments: 4 fully-coalesced 1KB loads (overlap prologue DMA)
    const unsigned char* fA = ws + REFF_OFF
        + ((size_t)(b * H_N + h) * 12 + wt) * 4096 + (size_t)lane * 16;
    const s16x8 A0 = *(const s16x8*)(fA);
    const s16x8 A1 = *(const s16x8*)(fA + 1024);
    const s16x8 A2 = *(const s16x8*)(fA + 2048);
    const s16x8 A3 = *(const s16x8*)(fA + 3072);

    const float* r2p = (const float*)(ws + R2_OFF) + bT + h * W_N + w0;
    const f32x4 r2v = *(const f32x4*)(r2p + grp * 4);

    const float* t2pl = (const float*)(ws + T2_OFF) + bT;

    float* outb = out + (size_t)b * 81 * TPLANE + (size_t)ig * 27 * TPLANE
                + h * W_N + w0;
    const size_t so0 = (size_t)grp * TPLANE + col;        // j=grp
    const size_t so1 = (size_t)(4 + grp) * TPLANE + col;  // j=4+grp
    const size_t so2 = (size_t)8 * TPLANE + col;          // j=8

#pragma unroll
    for (int tt = 0; tt < 3; ++tt) {
        const int row = rowbase + tt;
        const bool rok = (unsigned)row < (unsigned)H_N;   // block-uniform

        // barrier: (a) vmcnt drain completes stage(tt) — issued one full
        // compute phase ago; (b) all waves done reading buf[tt&1]^1.
        __syncthreads();

        // issue stage(tt+1) into the other buffer; flies under compute(tt)
        if (tt < 2) {
            const int nrow = row + 1;
            if ((unsigned)nrow < (unsigned)H_N) {
                const unsigned char* fB = tgtF + (size_t)(b * H_N + nrow) * FRAG_ROW_SZ
                                        + (size_t)(wt0 + wv) * 4096 + (size_t)lane * 16;
                unsigned char* lp = &stageB[(tt + 1) & 1][0] + wv * 4096;
                GLL16(fB,        lp);
                GLL16(fB + 1024, lp + 1024);
                GLL16(fB + 2048, lp + 2048);
                GLL16(fB + 3072, lp + 3072);
            }
        }

        // ---- compute row tt from stageB[tt&1] + reg-loaded edge tile ----
        f32x4 acc0 = {0.f, 0.f, 0.f, 0.f}, acc1 = acc0, acc2 = acc0;
        float t20 = 0.f, t21 = 0.f, t22 = 0.f;

        if (rok) {
            const float* t2r = t2pl + row * W_N;
            // edge tile regs (wv0 left / wv3 right only), issued early (L2-hot)
            s16x8 E0, E1, E2, E3;
            if (eok) {
                const unsigned char* ep = tgtF
                    + (size_t)(b * H_N + row) * FRAG_ROW_SZ
                    + (size_t)eq * 4096 + (size_t)lane * 16;
                E0 = *(const s16x8*)(ep);
                E1 = *(const s16x8*)(ep + 1024);
                E2 = *(const s16x8*)(ep + 2048);
                E3 = *(const s16x8*)(ep + 3072);
            }
            if (dok0) t20 = t2r[(wt - 1) * 16 + col];
            t21 = t2r[wt * 16 + col];
            if (dok2) t22 = t2r[(wt + 1) * 16 + col];

            const unsigned char* sb = &stageB[tt & 1][0] + (size_t)lane * 16;
            // d=1 (center, staged index wv) — always staged, do first
            {
                const unsigned char* p = sb + (size_t)wv * 4096;
                const s16x8 B0 = *(const s16x8*)(p);
                const s16x8 B1 = *(const s16x8*)(p + 1024);
                const s16x8 B2 = *(const s16x8*)(p + 2048);
                const s16x8 B3 = *(const s16x8*)(p + 3072);
                acc1 = MFMA_B16(A0, B0, acc1, 0, 0, 0);
                acc1 = MFMA_B16(A1, B1, acc1, 0, 0, 0);
                acc1 = MFMA_B16(A2, B2, acc1, 0, 0, 0);
                acc1 = MFMA_B16(A3, B3, acc1, 0, 0, 0);
            }
            // d=2 (staged for wv<3; edge regs for wv==3)
            if (dok2) {
                if (wv < 3) {
                    const unsigned char* p = sb + (size_t)(wv + 1) * 4096;
                    const s16x8 B0 = *(const s16x8*)(p);
                    const s16x8 B1 = *(const s16x8*)(p + 1024);
                    const s16x8 B2 = *(const s16x8*)(p + 2048);
                    const s16x8 B3 = *(const s16x8*)(p + 3072);
                    acc2 = MFMA_B16(A0, B0, acc2, 0, 0, 0);
                    acc2 = MFMA_B16(A1, B1, acc2, 0, 0, 0);
                    acc2 = MFMA_B16(A2, B2, acc2, 0, 0, 0);
                    acc2 = MFMA_B16(A3, B3, acc2, 0, 0, 0);
                } else {
                    acc2 = MFMA_B16(A0, E0, acc2, 0, 0, 0);
                    acc2 = MFMA_B16(A1, E1, acc2, 0, 0, 0);
                    acc2 = MFMA_B16(A2, E2, acc2, 0, 0, 0);
                    acc2 = MFMA_B16(A3, E3, acc2, 0, 0, 0);
                }
            }
            // d=0 (staged for wv>0; edge regs for wv==0) — edge last
            if (dok0) {
                if (wv > 0) {
                    const unsigned char* p = sb + (size_t)(wv - 1) * 4096;
                    const s16x8 B0 = *(const s16x8*)(p);
                    const s16x8 B1 = *(const s16x8*)(p + 1024);
                    const s16x8 B2 = *(const s16x8*)(p + 2048);
                    const s16x8 B3 = *(const s16x8*)(p + 3072);
                    acc0 = MFMA_B16(A0, B0, acc0, 0, 0, 0);
                    acc0 = MFMA_B16(A1, B1, acc0, 0, 0, 0);
                    acc0 = MFMA_B16(A2, B2, acc0, 0, 0, 0);
                    acc0 = MFMA_B16(A3, B3, acc0, 0, 0, 0);
                } else {
                    acc0 = MFMA_B16(A0, E0, acc0, 0, 0, 0);
                    acc0 = MFMA_B16(A1, E1, acc0, 0, 0, 0);
                    acc0 = MFMA_B16(A2, E2, acc0, 0, 0, 0);
                    acc0 = MFMA_B16(A3, E3, acc0, 0, 0, 0);
                }
            }
        }

        // ---- extract: D col = lane&15 (q in tile), D row = grp*4+pp (w) ----
#pragma unroll
        for (int d = 0; d < 3; ++d) {
            const bool dok = (d == 0) ? dok0 : ((d == 1) ? true : dok2);
            const f32x4 ac = (d == 0) ? acc0 : ((d == 1) ? acc1 : acc2);
            const float t2 = (d == 0) ? t20 : ((d == 1) ? t21 : t22);
#pragma unroll
            for (int pp = 0; pp < 4; ++pp) {
                const int wl = grp * 4 + pp;
                const int j  = 16 * (d - 1) + col - wl + 4;
                if ((unsigned)j < 9u) {
                    float val = 0.f;
                    if (rok && dok) {
                        float cs_ = r2v[pp] + t2 - 2.f * ac[pp];
                        val = __builtin_amdgcn_sqrtf(fmaxf(cs_, 0.f));
                    }
                    ldsx[wv][wl][j] = val;   // within-wave use only
                }
            }
        }

        float* ob = outb + (size_t)tt * 9 * TPLANE;
        float v0 = ldsx[wv][col][grp];
        float v1 = ldsx[wv][col][4 + grp];
        ob[so0] = v0;
        ob[so1] = v1;
        if (lane < 16) ob[so2] = ldsx[wv][col][8];
    }
}

// ---------------- Fallback (round-3 kernel, used if ws too small) ----------
__global__ __launch_bounds__(256, 4)
void corrcost3(const float* __restrict__ ref,
               const float* __restrict__ tgt,
               float* __restrict__ out)
{
    const int tid  = threadIdx.x;
    const int lane = tid & 63;
    const int wv   = tid >> 6;
    const int bid = blockIdx.x;
    const int swz = (bid & 7) * 1296 + (bid >> 3);
    const int u   = swz * 4 + wv;
    const int i   = u % 9;
    const int v9  = u / 9;
    const int wt  = v9 % 12;
    const int v12 = v9 / 12;
    const int h   = v12 % 96;
    const int b   = v12 / 96;
    const int w0  = wt * 16;
    const int q0  = w0 - 8;
    const int row = h + i - 4;
    const bool rok = (unsigned)row < (unsigned)H_N;

    const float* ref_b = ref + (size_t)b * CPLANE;
    const float* tgt_b = tgt + (size_t)b * CPLANE;
    float* out_b = out + (size_t)b * 81 * TPLANE;
    const int col = lane & 15;
    const int ke  = (lane >> 4) * 8;

    s16x8 A[4];
    float r2p = 0.f;
    const float* aptr = ref_b + (size_t)ke * TPLANE + h * W_N + w0 + col;
#pragma unroll
    for (int kc = 0; kc < 4; ++kc) {
#pragma unroll
        for (int e = 0; e < 8; ++e) {
            float v = aptr[(size_t)(kc * 32 + e) * TPLANE];
            short s = f2bf(v);
            float vb = bf2f(s);
            r2p = fmaf(vb, vb, r2p);
            A[kc][e] = s;
        }
    }
    r2p += __shfl_xor(r2p, 16);
    r2p += __shfl_xor(r2p, 32);
    float r2r[4];
#pragma unroll
    for (int pp = 0; pp < 4; ++pp)
        r2r[pp] = __shfl(r2p, (lane >> 4) * 4 + pp);

    f32x4 acc0 = {0.f, 0.f, 0.f, 0.f}, acc1 = acc0;
    float t20 = 0.f, t21 = 0.f;
    if (rok) {
        const float* bbase = tgt_b + (size_t)ke * TPLANE + (size_t)row * W_N;
#pragma unroll
        for (int t = 0; t < 2; ++t) {
            const int q = q0 + t * 16 + col;
            const bool qok = (unsigned)q < (unsigned)W_N;
            const float* bptr = bbase + q;
            s16x8 Bf[4];
            float t2p = 0.f;
#pragma unroll
            for (int kc = 0; kc < 4; ++kc) {
#pragma unroll
                for (int e = 0; e < 8; ++e) {
                    float v = qok ? bptr[(size_t)(kc * 32 + e) * TPLANE] : 0.f;
                    short s = f2bf(v);
                    float vb = bf2f(s);
                    t2p = fmaf(vb, vb, t2p);
                    Bf[kc][e] = s;
                }
            }
            t2p += __shfl_xor(t2p, 16);
            t2p += __shfl_xor(t2p, 32);
            if (t == 0) {
                t20 = t2p;
#pragma unroll
                for (int kc = 0; kc < 4; ++kc)
                    acc0 = MFMA_B16(A[kc], Bf[kc], acc0, 0, 0, 0);
            } else {
                t21 = t2p;
#pragma unroll
                for (int kc = 0; kc < 4; ++kc)
                    acc1 = MFMA_B16(A[kc], Bf[kc], acc1, 0, 0, 0);
            }
        }
    }
#pragma unroll
    for (int t = 0; t < 2; ++t) {
        const int q = q0 + t * 16 + col;
        const bool qok = (unsigned)q < (unsigned)W_N;
        const f32x4 a = t ? acc1 : acc0;
        const float t2 = t ? t21 : t20;
#pragma unroll
        for (int pp = 0; pp < 4; ++pp) {
            const int wl = (lane >> 4) * 4 + pp;
            const int j  = q - (w0 + wl) + 4;
            if ((unsigned)j < 9u) {
                float val = 0.f;
                if (rok && qok) {
                    float cs = r2r[pp] + t2 - 2.f * a[pp];
                    val = cs > 0.f ? sqrtf(cs) : 0.f;
                }
                out_b[(size_t)(i * 9 + j) * TPLANE + h * W_N + w0 + wl] = val;
            }
        }
    }
}

extern "C" void kernel_launch(void* const* d_in, const int* in_sizes, int n_in,
                              void* d_out, int out_size, void* d_ws, size_t ws_size,
                              hipStream_t stream) {
    const float* ref = (const float*)d_in[0];
    const float* tgt = (const float*)d_in[1];
    float* out = (float*)d_out;

    if (ws_size >= WS_NEED && d_ws != nullptr) {
        unsigned char* ws = (unsigned char*)d_ws;
        convert_frag<<<dim3(3 * H_N * B_N, 2), dim3(256), 0, stream>>>(ref, tgt, ws);
        corrcost19<<<dim3(3456), dim3(256), 0, stream>>>(ws, out);
    } else {
        corrcost3<<<dim3(10368), dim3(256), 0, stream>>>(ref, tgt, out);
    }
}

// Round 21
// 46.011 us; speedup vs baseline: 1.0744x; 1.0381x over previous
//
#include <hip/hip_runtime.h>

// DifferenceCost, two-pass, fragment-major workspace:
//  Pass A: fp32 [b][c][h][w] -> bf16 MFMA-fragment layout
//          frag[b][row][qtile(12)][kc(4)][lane(64)] (16B per lane), plus
//          per-pixel sum-of-squares planes R2/T2 (on bf16-rounded values).
//  Pass B (corrcost20): MIN-LDS / MAX-RESIDENCY: 2-wave blocks (128 thr),
//          block=(b,h,wt-pair) x ig (6912 blocks, ig-innermost L2-hot grid).
//          Per row: each wave stages its own center qtile (8KB total) and
//          reg-loads its one edge qtile. LDS 9.7KB -> ~16 blocks/CU.
//          R18's proven 2-barrier/row structure. cost=sqrt(max(R2+T2-2X,0)).
// Falls back to round-3 single-kernel path if ws too small.

#define B_N 4
#define C_N 128
#define H_N 96
#define W_N 192
#define TPLANE (H_N * W_N)                 // 18432
#define CPLANE ((size_t)C_N * TPLANE)

#define FRAG_ROW_SZ ((size_t)12 * 4 * 1024)          // 49152 B per (b,row)
#define BF_SZ   ((size_t)B_N * H_N * FRAG_ROW_SZ)    // 18,874,368
#define REFF_OFF ((size_t)0)
#define TGTF_OFF BF_SZ
#define SQ_SZ   ((size_t)B_N * TPLANE * 4)
#define R2_OFF  (2 * BF_SZ)
#define T2_OFF  (R2_OFF + SQ_SZ)
#define WS_NEED (T2_OFF + SQ_SZ)                     // 38,338,560 B

using f32x4 = __attribute__((ext_vector_type(4))) float;
using s16x8 = __attribute__((ext_vector_type(8))) short;

typedef const __attribute__((address_space(1))) void* gas1_t;
typedef __attribute__((address_space(3))) void* las3_t;
#define GLL16(gp, lp) __builtin_amdgcn_global_load_lds((gas1_t)(gp), (las3_t)(lp), 16, 0, 0)

__device__ __forceinline__ short f2bf(float x) {
    unsigned u = __builtin_bit_cast(unsigned, x);
    u = (u + 0x7fffu + ((u >> 16) & 1u)) >> 16;   // RNE; inputs finite
    return (short)(unsigned short)u;
}
__device__ __forceinline__ float bf2f(short s) {
    return __builtin_bit_cast(float, ((unsigned)(unsigned short)s) << 16);
}

// ---------------- Pass A: convert + fragment-major store + squared sums ----
__global__ __launch_bounds__(256, 4)
void convert_frag(const float* __restrict__ ref, const float* __restrict__ tgt,
                  unsigned char* __restrict__ ws)
{
    __shared__ unsigned int l32[64][65];   // [w][c-pair], stride 65 -> no conflicts

    const int tid = threadIdx.x;
    // bijective XCD chunk swizzle, (b,h)-major order shared with pass B
    const int bid = blockIdx.x;
    const int u2  = (bid & 7) * 144 + (bid >> 3);   // 1152 = 8 x 144
    const int wc  = u2 % 3;               // which 64-w chunk
    const int h   = (u2 / 3) % H_N;
    const int b   = u2 / (3 * H_N);
    const int w0  = wc * 64;
    const int isT = blockIdx.y;

    const float* src = (isT ? tgt : ref) + (size_t)b * CPLANE + h * W_N + w0;
    unsigned char* dstF = ws + (isT ? TGTF_OFF : REFF_OFF);
    float* sq = (float*)(ws + (isT ? T2_OFF : R2_OFF));

    // phase 1: coalesced fp32 read, convert, pack pairs into LDS
    const int w  = tid & 63;
    const int cq = tid >> 6;
#pragma unroll
    for (int batch = 0; batch < 16; ++batch) {
        int cp = batch * 4 + cq;
        float v0 = src[(size_t)(2 * cp + 0) * TPLANE + w];
        float v1 = src[(size_t)(2 * cp + 1) * TPLANE + w];
        unsigned u = ((unsigned)(unsigned short)f2bf(v0))
                   | ((unsigned)(unsigned short)f2bf(v1) << 16);
        l32[w][cp] = u;
    }
    __syncthreads();

    // phase 2: fragment-major store; each wave-iter writes 1KB contiguous.
#pragma unroll
    for (int it = 0; it < 4; ++it) {
        int idx   = it * 256 + tid;        // 0..1023
        int lane2 = idx & 63;
        int kc    = (idx >> 6) & 3;
        int qt_l  = idx >> 8;              // 0..3
        int w_l   = qt_l * 16 + (lane2 & 15);
        int cp0   = kc * 16 + (lane2 >> 4) * 4;
        uint4 d = make_uint4(l32[w_l][cp0], l32[w_l][cp0 + 1],
                             l32[w_l][cp0 + 2], l32[w_l][cp0 + 3]);
        int qt = wc * 4 + qt_l;
        size_t off = (((size_t)(b * H_N + h) * 12 + qt) * 4 + kc) * 1024
                   + (size_t)lane2 * 16;
        *(uint4*)(dstF + off) = d;
    }

    // phase 3: per-pixel sum of squares (bf16-rounded)
    const int cs = tid & 15;
#pragma unroll
    for (int pass = 0; pass < 4; ++pass) {
        int wr = pass * 16 + (tid >> 4);
        float s = 0.f;
#pragma unroll
        for (int k2 = 0; k2 < 4; ++k2) {
            unsigned u = l32[wr][cs * 4 + k2];
            float lo = __builtin_bit_cast(float, u << 16);
            float hi = __builtin_bit_cast(float, u & 0xffff0000u);
            s = fmaf(lo, lo, fmaf(hi, hi, s));
        }
        s += __shfl_xor(s, 1); s += __shfl_xor(s, 2);
        s += __shfl_xor(s, 4); s += __shfl_xor(s, 8);
        if (cs == 0) sq[(size_t)(b * TPLANE + h * W_N + w0 + wr)] = s;
    }
}

// ---------------- Pass B: 2-wave blocks, 8KB stage, max residency ----------
#define MFMA_B16 __builtin_amdgcn_mfma_f32_16x16x32_bf16

__global__ __launch_bounds__(128)
void corrcost20(const unsigned char* __restrict__ ws, float* __restrict__ out)
{
    __shared__ unsigned char stageB[2 * 4096];   // 2 center qtiles, 8 KiB
    __shared__ float ldsx[2][16][12];            // extract transpose, 1.5 KiB

    const int tid  = threadIdx.x;
    const int lane = tid & 63;
    const int wv   = tid >> 6;        // 0..1
    const int col  = lane & 15;
    const int grp  = lane >> 4;

    // 6912 blocks = 8 XCDs x 864 (bijective). u = ((b*96+h)*6+wtp)*3+ig:
    // ig innermost -> all readers of a tgt row temporally adjacent (L2-hot).
    const int blk = blockIdx.x;
    const int u   = (blk & 7) * 864 + (blk >> 3);
    const int ig  = u % 3;
    const int r3  = u / 3;
    const int wtp = r3 % 6;
    const int v3  = r3 / 6;
    const int h   = v3 % 96;
    const int b   = v3 / 96;
    const int bT  = b * TPLANE;

    const int wt0 = wtp * 2;
    const int wt  = wt0 + wv;
    const int w0  = wt * 16;

    const bool dok0 = (wt >= 1);
    const bool dok2 = (wt <= 10);
    // each wave has exactly one edge qtile outside the 2 staged center tiles
    const int eq  = (wv == 0) ? (wt0 - 1) : (wt0 + 2);
    const bool eok = (unsigned)eq < 12u;
    const int edge_d = (wv == 0) ? 0 : 2;   // which d uses the edge tile

    // A fragments: 4 fully-coalesced 1KB loads (per wave, its own wt)
    const unsigned char* fA = ws + REFF_OFF
        + ((size_t)(b * H_N + h) * 12 + wt) * 4096 + (size_t)lane * 16;
    const s16x8 A0 = *(const s16x8*)(fA);
    const s16x8 A1 = *(const s16x8*)(fA + 1024);
    const s16x8 A2 = *(const s16x8*)(fA + 2048);
    const s16x8 A3 = *(const s16x8*)(fA + 3072);

    const float* r2p = (const float*)(ws + R2_OFF) + bT + h * W_N + w0;
    const f32x4 r2v = *(const f32x4*)(r2p + grp * 4);

    const float* t2pl = (const float*)(ws + T2_OFF) + bT;
    const unsigned char* tgtF = ws + TGTF_OFF;

    float* outb = out + (size_t)b * 81 * TPLANE + (size_t)ig * 27 * TPLANE
                + h * W_N + w0;
    const size_t so0 = (size_t)grp * TPLANE + col;        // j=grp
    const size_t so1 = (size_t)(4 + grp) * TPLANE + col;  // j=4+grp
    const size_t so2 = (size_t)8 * TPLANE + col;          // j=8

    const int rowbase = h + ig * 3 - 4;

#pragma unroll
    for (int tt = 0; tt < 3; ++tt) {
        const int row = rowbase + tt;
        const bool rok = (unsigned)row < (unsigned)H_N;   // block-uniform

        // ---- stage this wave's center qtile for this row (4 GLL16) ----
        if (rok) {
            const unsigned char* fB = tgtF + (size_t)(b * H_N + row) * FRAG_ROW_SZ
                                    + (size_t)wt * 4096 + (size_t)lane * 16;
            unsigned char* lp = stageB + wv * 4096;
            GLL16(fB,        lp);
            GLL16(fB + 1024, lp + 1024);
            GLL16(fB + 2048, lp + 2048);
            GLL16(fB + 3072, lp + 3072);
        }
        __syncthreads();                 // drains vmcnt -> staged data visible

        // ---- compute from LDS + reg-loaded edge tile ----
        f32x4 acc0 = {0.f, 0.f, 0.f, 0.f}, acc1 = acc0, acc2 = acc0;
        float t20 = 0.f, t21 = 0.f, t22 = 0.f;

        if (rok) {
            const float* t2r = t2pl + row * W_N;
            // edge tile regs (one per wave), issued early (L2-hot)
            s16x8 E0, E1, E2, E3;
            if (eok) {
                const unsigned char* ep = tgtF
                    + (size_t)(b * H_N + row) * FRAG_ROW_SZ
                    + (size_t)eq * 4096 + (size_t)lane * 16;
                E0 = *(const s16x8*)(ep);
                E1 = *(const s16x8*)(ep + 1024);
                E2 = *(const s16x8*)(ep + 2048);
                E3 = *(const s16x8*)(ep + 3072);
            }
            if (dok0) t20 = t2r[(wt - 1) * 16 + col];
            t21 = t2r[wt * 16 + col];
            if (dok2) t22 = t2r[(wt + 1) * 16 + col];

            const unsigned char* sb = stageB + (size_t)lane * 16;
            // d=1 (own center tile, staged at ql = wv) — always staged, first
            {
                const unsigned char* p = sb + (size_t)wv * 4096;
                const s16x8 B0 = *(const s16x8*)(p);
                const s16x8 B1 = *(const s16x8*)(p + 1024);
                const s16x8 B2 = *(const s16x8*)(p + 2048);
                const s16x8 B3 = *(const s16x8*)(p + 3072);
                acc1 = MFMA_B16(A0, B0, acc1, 0, 0, 0);
                acc1 = MFMA_B16(A1, B1, acc1, 0, 0, 0);
                acc1 = MFMA_B16(A2, B2, acc1, 0, 0, 0);
                acc1 = MFMA_B16(A3, B3, acc1, 0, 0, 0);
            }
            // the other staged tile: wv0 -> d=2 (ql1); wv1 -> d=0 (ql0)
            {
                const bool sdok = (wv == 0) ? dok2 : dok0;
                if (sdok) {
                    const unsigned char* p = sb + (size_t)(wv ^ 1) * 4096;
                    const s16x8 B0 = *(const s16x8*)(p);
                    const s16x8 B1 = *(const s16x8*)(p + 1024);
                    const s16x8 B2 = *(const s16x8*)(p + 2048);
                    const s16x8 B3 = *(const s16x8*)(p + 3072);
                    f32x4 t = (wv == 0) ? acc2 : acc0;
                    t = MFMA_B16(A0, B0, t, 0, 0, 0);
                    t = MFMA_B16(A1, B1, t, 0, 0, 0);
                    t = MFMA_B16(A2, B2, t, 0, 0, 0);
                    t = MFMA_B16(A3, B3, t, 0, 0, 0);
                    if (wv == 0) acc2 = t; else acc0 = t;
                }
            }
            // edge tile: wv0 -> d=0; wv1 -> d=2
            if (eok) {
                f32x4 t = (wv == 0) ? acc0 : acc2;
                t = MFMA_B16(A0, E0, t, 0, 0, 0);
                t = MFMA_B16(A1, E1, t, 0, 0, 0);
                t = MFMA_B16(A2, E2, t, 0, 0, 0);
                t = MFMA_B16(A3, E3, t, 0, 0, 0);
                if (wv == 0) acc0 = t; else acc2 = t;
            }
        }

        // ---- extract: D col = lane&15 (q in tile), D row = grp*4+pp (w) ----
#pragma unroll
        for (int d = 0; d < 3; ++d) {
            const bool dok = (d == 0) ? dok0 : ((d == 1) ? true : dok2);
            const f32x4 ac = (d == 0) ? acc0 : ((d == 1) ? acc1 : acc2);
            const float t2 = (d == 0) ? t20 : ((d == 1) ? t21 : t22);
#pragma unroll
            for (int pp = 0; pp < 4; ++pp) {
                const int wl = grp * 4 + pp;
                const int j  = 16 * (d - 1) + col - wl + 4;
                if ((unsigned)j < 9u) {
                    float val = 0.f;
                    if (rok && dok) {
                        float cs_ = r2v[pp] + t2 - 2.f * ac[pp];
                        val = __builtin_amdgcn_sqrtf(fmaxf(cs_, 0.f));
                    }
                    ldsx[wv][wl][j] = val;   // within-wave use only
                }
            }
        }

        float* ob = outb + (size_t)tt * 9 * TPLANE;
        float v0 = ldsx[wv][col][grp];
        float v1 = ldsx[wv][col][4 + grp];
        ob[so0] = v0;
        ob[so1] = v1;
        if (lane < 16) ob[so2] = ldsx[wv][col][8];

        __syncthreads();                 // all reads done before next-row DMA
    }
}

// ---------------- Fallback (round-3 kernel, used if ws too small) ----------
__global__ __launch_bounds__(256, 4)
void corrcost3(const float* __restrict__ ref,
               const float* __restrict__ tgt,
               float* __restrict__ out)
{
    const int tid  = threadIdx.x;
    const int lane = tid & 63;
    const int wv   = tid >> 6;
    const int bid = blockIdx.x;
    const int swz = (bid & 7) * 1296 + (bid >> 3);
    const int u   = swz * 4 + wv;
    const int i   = u % 9;
    const int v9  = u / 9;
    const int wt  = v9 % 12;
    const int v12 = v9 / 12;
    const int h   = v12 % 96;
    const int b   = v12 / 96;
    const int w0  = wt * 16;
    const int q0  = w0 - 8;
    const int row = h + i - 4;
    const bool rok = (unsigned)row < (unsigned)H_N;

    const float* ref_b = ref + (size_t)b * CPLANE;
    const float* tgt_b = tgt + (size_t)b * CPLANE;
    float* out_b = out + (size_t)b * 81 * TPLANE;
    const int col = lane & 15;
    const int ke  = (lane >> 4) * 8;

    s16x8 A[4];
    float r2p = 0.f;
    const float* aptr = ref_b + (size_t)ke * TPLANE + h * W_N + w0 + col;
#pragma unroll
    for (int kc = 0; kc < 4; ++kc) {
#pragma unroll
        for (int e = 0; e < 8; ++e) {
            float v = aptr[(size_t)(kc * 32 + e) * TPLANE];
            short s = f2bf(v);
            float vb = bf2f(s);
            r2p = fmaf(vb, vb, r2p);
            A[kc][e] = s;
        }
    }
    r2p += __shfl_xor(r2p, 16);
    r2p += __shfl_xor(r2p, 32);
    float r2r[4];
#pragma unroll
    for (int pp = 0; pp < 4; ++pp)
        r2r[pp] = __shfl(r2p, (lane >> 4) * 4 + pp);

    f32x4 acc0 = {0.f, 0.f, 0.f, 0.f}, acc1 = acc0;
    float t20 = 0.f, t21 = 0.f;
    if (rok) {
        const float* bbase = tgt_b + (size_t)ke * TPLANE + (size_t)row * W_N;
#pragma unroll
        for (int t = 0; t < 2; ++t) {
            const int q = q0 + t * 16 + col;
            const bool qok = (unsigned)q < (unsigned)W_N;
            const float* bptr = bbase + q;
            s16x8 Bf[4];
            float t2p = 0.f;
#pragma unroll
            for (int kc = 0; kc < 4; ++kc) {
#pragma unroll
                for (int e = 0; e < 8; ++e) {
                    float v = qok ? bptr[(size_t)(kc * 32 + e) * TPLANE] : 0.f;
                    short s = f2bf(v);
                    float vb = bf2f(s);
                    t2p = fmaf(vb, vb, t2p);
                    Bf[kc][e] = s;
                }
            }
            t2p += __shfl_xor(t2p, 16);
            t2p += __shfl_xor(t2p, 32);
            if (t == 0) {
                t20 = t2p;
#pragma unroll
                for (int kc = 0; kc < 4; ++kc)
                    acc0 = MFMA_B16(A[kc], Bf[kc], acc0, 0, 0, 0);
            } else {
                t21 = t2p;
#pragma unroll
                for (int kc = 0; kc < 4; ++kc)
                    acc1 = MFMA_B16(A[kc], Bf[kc], acc1, 0, 0, 0);
            }
        }
    }
#pragma unroll
    for (int t = 0; t < 2; ++t) {
        const int q = q0 + t * 16 + col;
        const bool qok = (unsigned)q < (unsigned)W_N;
        const f32x4 a = t ? acc1 : acc0;
        const float t2 = t ? t21 : t20;
#pragma unroll
        for (int pp = 0; pp < 4; ++pp) {
            const int wl = (lane >> 4) * 4 + pp;
            const int j  = q - (w0 + wl) + 4;
            if ((unsigned)j < 9u) {
                float val = 0.f;
                if (rok && qok) {
                    float cs = r2r[pp] + t2 - 2.f * a[pp];
                    val = cs > 0.f ? sqrtf(cs) : 0.f;
                }
                out_b[(size_t)(i * 9 + j) * TPLANE + h * W_N + w0 + wl] = val;
            }
        }
    }
}

extern "C" void kernel_launch(void* const* d_in, const int* in_sizes, int n_in,
                              void* d_out, int out_size, void* d_ws, size_t ws_size,
                              hipStream_t stream) {
    const float* ref = (const float*)d_in[0];
    const float* tgt = (const float*)d_in[1];
    float* out = (float*)d_out;

    if (ws_size >= WS_NEED && d_ws != nullptr) {
        unsigned char* ws = (unsigned char*)d_ws;
        convert_frag<<<dim3(3 * H_N * B_N, 2), dim3(256), 0, stream>>>(ref, tgt, ws);
        corrcost20<<<dim3(6912), dim3(128), 0, stream>>>(ws, out);
    } else {
        corrcost3<<<dim3(10368), dim3(256), 0, stream>>>(ref, tgt, out);
    }
}

// Round 22
// 45.371 us; speedup vs baseline: 1.0896x; 1.0141x over previous
//
#include <hip/hip_runtime.h>

// DifferenceCost, two-pass, fragment-major workspace (BEST CONFIG, R18=45.4us):
//  Pass A: fp32 [b][c][h][w] -> bf16 MFMA-fragment layout
//          frag[b][row][qtile(12)][kc(4)][lane(64)] (16B per lane), plus
//          per-pixel sum-of-squares planes R2/T2 (on bf16-rounded values).
//  Pass B (corrcost17): block=(b,h,wtg) x ig folded innermost into grid.x
//          (3456 = 8 XCDs x 432, bijective chunked swizzle) -> all readers
//          of a tgt row temporally adjacent, ws reads L2-hit. Per row: the
//          4 waves stage the 4 CENTER qtiles (16KB LDS); edge qtiles (wv0
//          left / wv3 right) go global->registers. 19KB LDS -> ~7 blocks/CU.
//          cost = sqrt(max(R2+T2-2X,0)).
// Falls back to round-3 single-kernel path if ws too small.

#define B_N 4
#define C_N 128
#define H_N 96
#define W_N 192
#define TPLANE (H_N * W_N)                 // 18432
#define CPLANE ((size_t)C_N * TPLANE)

#define FRAG_ROW_SZ ((size_t)12 * 4 * 1024)          // 49152 B per (b,row)
#define BF_SZ   ((size_t)B_N * H_N * FRAG_ROW_SZ)    // 18,874,368
#define REFF_OFF ((size_t)0)
#define TGTF_OFF BF_SZ
#define SQ_SZ   ((size_t)B_N * TPLANE * 4)
#define R2_OFF  (2 * BF_SZ)
#define T2_OFF  (R2_OFF + SQ_SZ)
#define WS_NEED (T2_OFF + SQ_SZ)                     // 38,338,560 B

using f32x4 = __attribute__((ext_vector_type(4))) float;
using s16x8 = __attribute__((ext_vector_type(8))) short;

typedef const __attribute__((address_space(1))) void* gas1_t;
typedef __attribute__((address_space(3))) void* las3_t;
#define GLL16(gp, lp) __builtin_amdgcn_global_load_lds((gas1_t)(gp), (las3_t)(lp), 16, 0, 0)

__device__ __forceinline__ short f2bf(float x) {
    unsigned u = __builtin_bit_cast(unsigned, x);
    u = (u + 0x7fffu + ((u >> 16) & 1u)) >> 16;   // RNE; inputs finite
    return (short)(unsigned short)u;
}
__device__ __forceinline__ float bf2f(short s) {
    return __builtin_bit_cast(float, ((unsigned)(unsigned short)s) << 16);
}

// ---------------- Pass A: convert + fragment-major store + squared sums ----
__global__ __launch_bounds__(256, 4)
void convert_frag(const float* __restrict__ ref, const float* __restrict__ tgt,
                  unsigned char* __restrict__ ws)
{
    __shared__ unsigned int l32[64][65];   // [w][c-pair], stride 65 -> no conflicts

    const int tid = threadIdx.x;
    // bijective XCD chunk swizzle, (b,h)-major order shared with pass B
    const int bid = blockIdx.x;
    const int u2  = (bid & 7) * 144 + (bid >> 3);   // 1152 = 8 x 144
    const int wc  = u2 % 3;               // which 64-w chunk
    const int h   = (u2 / 3) % H_N;
    const int b   = u2 / (3 * H_N);
    const int w0  = wc * 64;
    const int isT = blockIdx.y;

    const float* src = (isT ? tgt : ref) + (size_t)b * CPLANE + h * W_N + w0;
    unsigned char* dstF = ws + (isT ? TGTF_OFF : REFF_OFF);
    float* sq = (float*)(ws + (isT ? T2_OFF : R2_OFF));

    // phase 1: coalesced fp32 read, convert, pack pairs into LDS
    const int w  = tid & 63;
    const int cq = tid >> 6;
#pragma unroll
    for (int batch = 0; batch < 16; ++batch) {
        int cp = batch * 4 + cq;
        float v0 = src[(size_t)(2 * cp + 0) * TPLANE + w];
        float v1 = src[(size_t)(2 * cp + 1) * TPLANE + w];
        unsigned u = ((unsigned)(unsigned short)f2bf(v0))
                   | ((unsigned)(unsigned short)f2bf(v1) << 16);
        l32[w][cp] = u;
    }
    __syncthreads();

    // phase 2: fragment-major store; each wave-iter writes 1KB contiguous.
#pragma unroll
    for (int it = 0; it < 4; ++it) {
        int idx   = it * 256 + tid;        // 0..1023
        int lane2 = idx & 63;
        int kc    = (idx >> 6) & 3;
        int qt_l  = idx >> 8;              // 0..3
        int w_l   = qt_l * 16 + (lane2 & 15);
        int cp0   = kc * 16 + (lane2 >> 4) * 4;
        uint4 d = make_uint4(l32[w_l][cp0], l32[w_l][cp0 + 1],
                             l32[w_l][cp0 + 2], l32[w_l][cp0 + 3]);
        int qt = wc * 4 + qt_l;
        size_t off = (((size_t)(b * H_N + h) * 12 + qt) * 4 + kc) * 1024
                   + (size_t)lane2 * 16;
        *(uint4*)(dstF + off) = d;
    }

    // phase 3: per-pixel sum of squares (bf16-rounded)
    const int cs = tid & 15;
#pragma unroll
    for (int pass = 0; pass < 4; ++pass) {
        int wr = pass * 16 + (tid >> 4);
        float s = 0.f;
#pragma unroll
        for (int k2 = 0; k2 < 4; ++k2) {
            unsigned u = l32[wr][cs * 4 + k2];
            float lo = __builtin_bit_cast(float, u << 16);
            float hi = __builtin_bit_cast(float, u & 0xffff0000u);
            s = fmaf(lo, lo, fmaf(hi, hi, s));
        }
        s += __shfl_xor(s, 1); s += __shfl_xor(s, 2);
        s += __shfl_xor(s, 4); s += __shfl_xor(s, 8);
        if (cs == 0) sq[(size_t)(b * TPLANE + h * W_N + w0 + wr)] = s;
    }
}

// ---------------- Pass B: 4-center-tile staged, ig innermost in grid.x -----
#define MFMA_B16 __builtin_amdgcn_mfma_f32_16x16x32_bf16

__global__ __launch_bounds__(256)
void corrcost17(const unsigned char* __restrict__ ws, float* __restrict__ out)
{
    __shared__ unsigned char stageB[4 * 4096];   // 4 center qtiles, 16 KiB
    __shared__ float ldsx[4][16][12];            // extract transpose, 3 KiB

    const int tid  = threadIdx.x;
    const int lane = tid & 63;
    const int wv   = tid >> 6;
    const int col  = lane & 15;
    const int grp  = lane >> 4;

    // 3456 blocks = 8 XCDs x 432 (bijective chunked swizzle).
    // u = ((b*96+h)*3 + wtg)*3 + ig  -> ig innermost, wtg next, bh outer:
    // all readers of a tgt row / reusers of an A-frag are temporally adjacent.
    const int blk = blockIdx.x;
    const int u   = (blk & 7) * 432 + (blk >> 3);
    const int ig  = u % 3;
    const int r3  = u / 3;
    const int wtg = r3 % 3;
    const int v3  = r3 / 3;
    const int h   = v3 % 96;
    const int b   = v3 / 96;
    const int bT  = b * TPLANE;

    const int wt0 = wtg * 4;
    const int wt  = wt0 + wv;
    const int w0  = wt * 16;

    const bool dok0 = (wt >= 1);
    const bool dok2 = (wt <= 10);
    // this wave's edge qtile (outside the staged 4 center tiles), if any
    const int eq = (wv == 0) ? (wt0 - 1) : ((wv == 3) ? (wt0 + 4) : -1);
    const bool eok = (unsigned)eq < 12u;

    // A fragments: 4 fully-coalesced 1KB loads (per wave, its own wt)
    const unsigned char* fA = ws + REFF_OFF
        + ((size_t)(b * H_N + h) * 12 + wt) * 4096 + (size_t)lane * 16;
    const s16x8 A0 = *(const s16x8*)(fA);
    const s16x8 A1 = *(const s16x8*)(fA + 1024);
    const s16x8 A2 = *(const s16x8*)(fA + 2048);
    const s16x8 A3 = *(const s16x8*)(fA + 3072);

    const float* r2p = (const float*)(ws + R2_OFF) + bT + h * W_N + w0;
    const f32x4 r2v = *(const f32x4*)(r2p + grp * 4);

    const float* t2pl = (const float*)(ws + T2_OFF) + bT;
    const unsigned char* tgtF = ws + TGTF_OFF;

    float* outb = out + (size_t)b * 81 * TPLANE + (size_t)ig * 27 * TPLANE
                + h * W_N + w0;
    const size_t so0 = (size_t)grp * TPLANE + col;        // j=grp
    const size_t so1 = (size_t)(4 + grp) * TPLANE + col;  // j=4+grp
    const size_t so2 = (size_t)8 * TPLANE + col;          // j=8

    const int rowbase = h + ig * 3 - 4;

#pragma unroll
    for (int tt = 0; tt < 3; ++tt) {
        const int row = rowbase + tt;
        const bool rok = (unsigned)row < (unsigned)H_N;   // block-uniform

        // ---- stage the 4 center qtiles for this row (1 tile per wave) ----
        if (rok) {
            const unsigned char* fB = tgtF + (size_t)(b * H_N + row) * FRAG_ROW_SZ
                                    + (size_t)(wt0 + wv) * 4096 + (size_t)lane * 16;
            unsigned char* lp = stageB + wv * 4096;
            GLL16(fB,        lp);
            GLL16(fB + 1024, lp + 1024);
            GLL16(fB + 2048, lp + 2048);
            GLL16(fB + 3072, lp + 3072);
        }
        __syncthreads();                 // drains vmcnt -> staged data visible

        // ---- compute from LDS + reg-loaded edge tile ----
        f32x4 acc0 = {0.f, 0.f, 0.f, 0.f}, acc1 = acc0, acc2 = acc0;
        float t20 = 0.f, t21 = 0.f, t22 = 0.f;

        if (rok) {
            const float* t2r = t2pl + row * W_N;
            // edge tile regs (wv0 left / wv3 right only), issued early (L2-hot)
            s16x8 E0, E1, E2, E3;
            if (eok) {
                const unsigned char* ep = tgtF
                    + (size_t)(b * H_N + row) * FRAG_ROW_SZ
                    + (size_t)eq * 4096 + (size_t)lane * 16;
                E0 = *(const s16x8*)(ep);
                E1 = *(const s16x8*)(ep + 1024);
                E2 = *(const s16x8*)(ep + 2048);
                E3 = *(const s16x8*)(ep + 3072);
            }
            if (dok0) t20 = t2r[(wt - 1) * 16 + col];
            t21 = t2r[wt * 16 + col];
            if (dok2) t22 = t2r[(wt + 1) * 16 + col];

            const unsigned char* sb = stageB + (size_t)lane * 16;
            // d=1 (center, staged index wv) — always staged, do first
            {
                const unsigned char* p = sb + (size_t)wv * 4096;
                const s16x8 B0 = *(const s16x8*)(p);
                const s16x8 B1 = *(const s16x8*)(p + 1024);
                const s16x8 B2 = *(const s16x8*)(p + 2048);
                const s16x8 B3 = *(const s16x8*)(p + 3072);
                acc1 = MFMA_B16(A0, B0, acc1, 0, 0, 0);
                acc1 = MFMA_B16(A1, B1, acc1, 0, 0, 0);
                acc1 = MFMA_B16(A2, B2, acc1, 0, 0, 0);
                acc1 = MFMA_B16(A3, B3, acc1, 0, 0, 0);
            }
            // d=2 (staged for wv<3; edge regs for wv==3)
            if (dok2) {
                if (wv < 3) {
                    const unsigned char* p = sb + (size_t)(wv + 1) * 4096;
                    const s16x8 B0 = *(const s16x8*)(p);
                    const s16x8 B1 = *(const s16x8*)(p + 1024);
                    const s16x8 B2 = *(const s16x8*)(p + 2048);
                    const s16x8 B3 = *(const s16x8*)(p + 3072);
                    acc2 = MFMA_B16(A0, B0, acc2, 0, 0, 0);
                    acc2 = MFMA_B16(A1, B1, acc2, 0, 0, 0);
                    acc2 = MFMA_B16(A2, B2, acc2, 0, 0, 0);
                    acc2 = MFMA_B16(A3, B3, acc2, 0, 0, 0);
                } else {
                    acc2 = MFMA_B16(A0, E0, acc2, 0, 0, 0);
                    acc2 = MFMA_B16(A1, E1, acc2, 0, 0, 0);
                    acc2 = MFMA_B16(A2, E2, acc2, 0, 0, 0);
                    acc2 = MFMA_B16(A3, E3, acc2, 0, 0, 0);
                }
            }
            // d=0 (staged for wv>0; edge regs for wv==0) — edge last
            if (dok0) {
                if (wv > 0) {
                    const unsigned char* p = sb + (size_t)(wv - 1) * 4096;
                    const s16x8 B0 = *(const s16x8*)(p);
                    const s16x8 B1 = *(const s16x8*)(p + 1024);
                    const s16x8 B2 = *(const s16x8*)(p + 2048);
                    const s16x8 B3 = *(const s16x8*)(p + 3072);
                    acc0 = MFMA_B16(A0, B0, acc0, 0, 0, 0);
                    acc0 = MFMA_B16(A1, B1, acc0, 0, 0, 0);
                    acc0 = MFMA_B16(A2, B2, acc0, 0, 0, 0);
                    acc0 = MFMA_B16(A3, B3, acc0, 0, 0, 0);
                } else {
                    acc0 = MFMA_B16(A0, E0, acc0, 0, 0, 0);
                    acc0 = MFMA_B16(A1, E1, acc0, 0, 0, 0);
                    acc0 = MFMA_B16(A2, E2, acc0, 0, 0, 0);
                    acc0 = MFMA_B16(A3, E3, acc0, 0, 0, 0);
                }
            }
        }

        // ---- extract: D col = lane&15 (q in tile), D row = grp*4+pp (w) ----
#pragma unroll
        for (int d = 0; d < 3; ++d) {
            const bool dok = (d == 0) ? dok0 : ((d == 1) ? true : dok2);
            const f32x4 ac = (d == 0) ? acc0 : ((d == 1) ? acc1 : acc2);
            const float t2 = (d == 0) ? t20 : ((d == 1) ? t21 : t22);
#pragma unroll
            for (int pp = 0; pp < 4; ++pp) {
                const int wl = grp * 4 + pp;
                const int j  = 16 * (d - 1) + col - wl + 4;
                if ((unsigned)j < 9u) {
                    float val = 0.f;
                    if (rok && dok) {
                        float cs_ = r2v[pp] + t2 - 2.f * ac[pp];
                        val = __builtin_amdgcn_sqrtf(fmaxf(cs_, 0.f));
                    }
                    ldsx[wv][wl][j] = val;   // within-wave use only
                }
            }
        }

        float* ob = outb + (size_t)tt * 9 * TPLANE;
        float v0 = ldsx[wv][col][grp];
        float v1 = ldsx[wv][col][4 + grp];
        ob[so0] = v0;
        ob[so1] = v1;
        if (lane < 16) ob[so2] = ldsx[wv][col][8];

        __syncthreads();                 // all reads done before next-row DMA
    }
}

// ---------------- Fallback (round-3 kernel, used if ws too small) ----------
__global__ __launch_bounds__(256, 4)
void corrcost3(const float* __restrict__ ref,
               const float* __restrict__ tgt,
               float* __restrict__ out)
{
    const int tid  = threadIdx.x;
    const int lane = tid & 63;
    const int wv   = tid >> 6;
    const int bid = blockIdx.x;
    const int swz = (bid & 7) * 1296 + (bid >> 3);
    const int u   = swz * 4 + wv;
    const int i   = u % 9;
    const int v9  = u / 9;
    const int wt  = v9 % 12;
    const int v12 = v9 / 12;
    const int h   = v12 % 96;
    const int b   = v12 / 96;
    const int w0  = wt * 16;
    const int q0  = w0 - 8;
    const int row = h + i - 4;
    const bool rok = (unsigned)row < (unsigned)H_N;

    const float* ref_b = ref + (size_t)b * CPLANE;
    const float* tgt_b = tgt + (size_t)b * CPLANE;
    float* out_b = out + (size_t)b * 81 * TPLANE;
    const int col = lane & 15;
    const int ke  = (lane >> 4) * 8;

    s16x8 A[4];
    float r2p = 0.f;
    const float* aptr = ref_b + (size_t)ke * TPLANE + h * W_N + w0 + col;
#pragma unroll
    for (int kc = 0; kc < 4; ++kc) {
#pragma unroll
        for (int e = 0; e < 8; ++e) {
            float v = aptr[(size_t)(kc * 32 + e) * TPLANE];
            short s = f2bf(v);
            float vb = bf2f(s);
            r2p = fmaf(vb, vb, r2p);
            A[kc][e] = s;
        }
    }
    r2p += __shfl_xor(r2p, 16);
    r2p += __shfl_xor(r2p, 32);
    float r2r[4];
#pragma unroll
    for (int pp = 0; pp < 4; ++pp)
        r2r[pp] = __shfl(r2p, (lane >> 4) * 4 + pp);

    f32x4 acc0 = {0.f, 0.f, 0.f, 0.f}, acc1 = acc0;
    float t20 = 0.f, t21 = 0.f;
    if (rok) {
        const float* bbase = tgt_b + (size_t)ke * TPLANE + (size_t)row * W_N;
#pragma unroll
        for (int t = 0; t < 2; ++t) {
            const int q = q0 + t * 16 + col;
            const bool qok = (unsigned)q < (unsigned)W_N;
            const float* bptr = bbase + q;
            s16x8 Bf[4];
            float t2p = 0.f;
#pragma unroll
            for (int kc = 0; kc < 4; ++kc) {
#pragma unroll
                for (int e = 0; e < 8; ++e) {
                    float v = qok ? bptr[(size_t)(kc * 32 + e) * TPLANE] : 0.f;
                    short s = f2bf(v);
                    float vb = bf2f(s);
                    t2p = fmaf(vb, vb, t2p);
                    Bf[kc][e] = s;
                }
            }
            t2p += __shfl_xor(t2p, 16);
            t2p += __shfl_xor(t2p, 32);
            if (t == 0) {
                t20 = t2p;
#pragma unroll
                for (int kc = 0; kc < 4; ++kc)
                    acc0 = MFMA_B16(A[kc], Bf[kc], acc0, 0, 0, 0);
            } else {
                t21 = t2p;
#pragma unroll
                for (int kc = 0; kc < 4; ++kc)
                    acc1 = MFMA_B16(A[kc], Bf[kc], acc1, 0, 0, 0);
            }
        }
    }
#pragma unroll
    for (int t = 0; t < 2; ++t) {
        const int q = q0 + t * 16 + col;
        const bool qok = (unsigned)q < (unsigned)W_N;
        const f32x4 a = t ? acc1 : acc0;
        const float t2 = t ? t21 : t20;
#pragma unroll
        for (int pp = 0; pp < 4; ++pp) {
            const int wl = (lane >> 4) * 4 + pp;
            const int j  = q - (w0 + wl) + 4;
            if ((unsigned)j < 9u) {
                float val = 0.f;
                if (rok && qok) {
                    float cs = r2r[pp] + t2 - 2.f * a[pp];
                    val = cs > 0.f ? sqrtf(cs) : 0.f;
                }
                out_b[(size_t)(i * 9 + j) * TPLANE + h * W_N + w0 + wl] = val;
            }
        }
    }
}

extern "C" void kernel_launch(void* const* d_in, const int* in_sizes, int n_in,
                              void* d_out, int out_size, void* d_ws, size_t ws_size,
                              hipStream_t stream) {
    const float* ref = (const float*)d_in[0];
    const float* tgt = (const float*)d_in[1];
    float* out = (float*)d_out;

    if (ws_size >= WS_NEED && d_ws != nullptr) {
        unsigned char* ws = (unsigned char*)d_ws;
        convert_frag<<<dim3(3 * H_N * B_N, 2), dim3(256), 0, stream>>>(ref, tgt, ws);
        corrcost17<<<dim3(3456), dim3(256), 0, stream>>>(ws, out);
    } else {
        corrcost3<<<dim3(10368), dim3(256), 0, stream>>>(ref, tgt, out);
    }
}